// Round 1
// baseline (155.313 us; speedup 1.0000x reference)
//
#include <hip/hip_runtime.h>

#define LC 2048
#define DD 128
#define LQ 64
#define NEGINF (-1e30f)

// K0: per-batch transpose Q -> Qt[b][j][d]; also sq[b][j] = sum_d Q[b][d][j]*w2[d]
__global__ __launch_bounds__(256) void k0_qt(const float* __restrict__ Q,
                                             const float* __restrict__ w,
                                             float* __restrict__ Qt,
                                             float* __restrict__ sqg) {
  __shared__ float s[DD][LQ + 1];
  int b = blockIdx.x;
  const float* Qb = Q + (size_t)b * DD * LQ;
  for (int k = threadIdx.x; k < DD * LQ; k += 256)
    s[k >> 6][k & 63] = Qb[k];
  __syncthreads();
  float* Qtb = Qt + (size_t)b * LQ * DD;
  for (int k = threadIdx.x; k < LQ * DD; k += 256) {
    int j = k >> 7, d = k & 127;
    Qtb[k] = s[d][j];
  }
  if (threadIdx.x < LQ) {
    int j = threadIdx.x;
    float acc = 0.f;
#pragma unroll
    for (int d = 0; d < DD; ++d) acc = fmaf(s[d][j], w[DD + d], acc);
    sqg[b * LQ + j] = acc;
  }
}

// K1: St[b][j][i] = sum_d C[b,d,i]*w3[d]*Q[b,d,j] + sc[i] + sq[j]
// grid (LC/128, B), 256 threads; thread tile 4i x 8j
__global__ __launch_bounds__(256) void k1_S(const float* __restrict__ C,
                                            const float* __restrict__ Q,
                                            const float* __restrict__ w,
                                            const float* __restrict__ sqg,
                                            float* __restrict__ St) {
  __shared__ float Cs[32][128];
  __shared__ float Qw[32][64];
  __shared__ float sqs[64];
  __shared__ float w1s[128];
  int b = blockIdx.y;
  int i0 = blockIdx.x * 128;
  int t = threadIdx.x;
  const float* Cb = C + (size_t)b * DD * LC;
  const float* Qb = Q + (size_t)b * DD * LQ;
  if (t < 128) w1s[t] = w[t];
  else if (t < 192) sqs[t - 128] = sqg[b * LQ + (t - 128)];
  int ig = t & 31, jg = t >> 5;
  float acc[4][8] = {};
  float asc[4] = {};
  for (int dc = 0; dc < DD; dc += 32) {
    __syncthreads();
    for (int k = t; k < 32 * 128; k += 256) {
      int dd = k >> 7, ii = k & 127;
      Cs[dd][ii] = Cb[(size_t)(dc + dd) * LC + i0 + ii];
    }
    for (int k = t; k < 32 * 64; k += 256) {
      int dd = k >> 6, j = k & 63;
      Qw[dd][j] = Qb[(dd + dc) * LQ + j] * w[2 * DD + dc + dd];
    }
    __syncthreads();
#pragma unroll 8
    for (int dd = 0; dd < 32; ++dd) {
      float4 c4 = *(const float4*)&Cs[dd][ig * 4];
      float cv[4] = {c4.x, c4.y, c4.z, c4.w};
      float qv[8];
      *(float4*)&qv[0] = *(const float4*)&Qw[dd][jg * 8];
      *(float4*)&qv[4] = *(const float4*)&Qw[dd][jg * 8 + 4];
      float w1v = w1s[dc + dd];
#pragma unroll
      for (int ii = 0; ii < 4; ++ii) {
        asc[ii] = fmaf(cv[ii], w1v, asc[ii]);
#pragma unroll
        for (int jj = 0; jj < 8; ++jj)
          acc[ii][jj] = fmaf(cv[ii], qv[jj], acc[ii][jj]);
      }
    }
  }
  float* Stb = St + (size_t)b * LQ * LC + i0;
#pragma unroll
  for (int jj = 0; jj < 8; ++jj) {
    int j = jg * 8 + jj;
    float sqv = sqs[j];
    float4 o = make_float4(acc[0][jj] + asc[0] + sqv,
                           acc[1][jj] + asc[1] + sqv,
                           acc[2][jj] + asc[2] + sqv,
                           acc[3][jj] + asc[3] + sqv);
    *(float4*)&Stb[(size_t)j * LC + ig * 4] = o;
  }
}

// K2: per-(b,j) column max + 1/sumexp over i (softmax axis=1 stats)
// grid B*16 blocks of 256; one wave per column
__global__ __launch_bounds__(256) void k2_stats(const float* __restrict__ St,
                                                float* __restrict__ M,
                                                float* __restrict__ Zi) {
  int b = blockIdx.x >> 4;
  int j = ((blockIdx.x & 15) << 2) + (threadIdx.x >> 6);
  int lane = threadIdx.x & 63;
  const float* col = St + ((size_t)b * LQ + j) * LC;
  const float4* col4 = (const float4*)col;
  float m = -3.4e38f;
  for (int k = lane; k < LC / 4; k += 64) {
    float4 v = col4[k];
    m = fmaxf(m, fmaxf(fmaxf(v.x, v.y), fmaxf(v.z, v.w)));
  }
#pragma unroll
  for (int off = 32; off > 0; off >>= 1) m = fmaxf(m, __shfl_xor(m, off, 64));
  float s = 0.f;
  for (int k = lane; k < LC / 4; k += 64) {
    float4 v = col4[k];
    s += __expf(v.x - m) + __expf(v.y - m) + __expf(v.z - m) + __expf(v.w - m);
  }
#pragma unroll
  for (int off = 32; off > 0; off >>= 1) s += __shfl_xor(s, off, 64);
  if (lane == 0) { M[b * LQ + j] = m; Zi[b * LQ + j] = 1.f / s; }
}

// K3: T[b][j][d] += sum_{i in chunk} exp(St-M)*Zi * C[b][d][i]
// grid (LC/128, B); LDS 64KB; thread tile 4j x 4d; atomicAdd into zeroed T
__global__ __launch_bounds__(256) void k3_T(const float* __restrict__ St,
                                            const float* __restrict__ C,
                                            const float* __restrict__ M,
                                            const float* __restrict__ Zi,
                                            float* __restrict__ T) {
  __shared__ float Es[128][64];
  __shared__ float Cs[128][64];
  int b = blockIdx.y;
  int i0 = blockIdx.x * 128;
  int t = threadIdx.x;
  {
    int j = t & 63, ig = t >> 6;  // ig 0..3: 32 i' each
    float mj = M[b * LQ + j], zj = Zi[b * LQ + j];
    const float* col = St + ((size_t)b * LQ + j) * LC + i0 + ig * 32;
#pragma unroll
    for (int k4 = 0; k4 < 8; ++k4) {
      float4 v = *(const float4*)&col[k4 * 4];
      Es[ig * 32 + k4 * 4 + 0][j] = __expf(v.x - mj) * zj;
      Es[ig * 32 + k4 * 4 + 1][j] = __expf(v.y - mj) * zj;
      Es[ig * 32 + k4 * 4 + 2][j] = __expf(v.z - mj) * zj;
      Es[ig * 32 + k4 * 4 + 3][j] = __expf(v.w - mj) * zj;
    }
  }
  int jg = t & 15, dg = t >> 4;
  const float* Cb = C + (size_t)b * DD * LC + i0;
  for (int h = 0; h < 2; ++h) {
    __syncthreads();
    {
      int dd = t & 63, ig = t >> 6;
      const float* src = Cb + (size_t)(h * 64 + dd) * LC + ig * 32;
#pragma unroll
      for (int k4 = 0; k4 < 8; ++k4) {
        float4 v = *(const float4*)&src[k4 * 4];
        Cs[ig * 32 + k4 * 4 + 0][dd] = v.x;
        Cs[ig * 32 + k4 * 4 + 1][dd] = v.y;
        Cs[ig * 32 + k4 * 4 + 2][dd] = v.z;
        Cs[ig * 32 + k4 * 4 + 3][dd] = v.w;
      }
    }
    __syncthreads();
    float a[4][4] = {};
    for (int ii = 0; ii < 128; ++ii) {
      float4 e4 = *(const float4*)&Es[ii][jg * 4];
      float4 c4 = *(const float4*)&Cs[ii][dg * 4];
      float ev[4] = {e4.x, e4.y, e4.z, e4.w};
      float cv[4] = {c4.x, c4.y, c4.z, c4.w};
#pragma unroll
      for (int jj = 0; jj < 4; ++jj)
#pragma unroll
        for (int kk = 0; kk < 4; ++kk)
          a[jj][kk] = fmaf(ev[jj], cv[kk], a[jj][kk]);
    }
#pragma unroll
    for (int jj = 0; jj < 4; ++jj)
#pragma unroll
      for (int kk = 0; kk < 4; ++kk)
        atomicAdd(&T[((size_t)b * LQ + jg * 4 + jj) * DD + h * 64 + dg * 4 + kk],
                  a[jj][kk]);
  }
}

// K4a: S1 row softmax (masked), stored tiled: S1B[b][tile16][j][i'128]
// grid (LC/256, B); thread per row
__global__ __launch_bounds__(256) void k4a_S1(const float* __restrict__ St,
                                              const float* __restrict__ qmask,
                                              float* __restrict__ S1B) {
  __shared__ float mk[64], nf[64];
  int b = blockIdx.y;
  int i = blockIdx.x * 256 + threadIdx.x;
  if (threadIdx.x < 64) {
    float m = qmask[b * LQ + threadIdx.x];
    mk[threadIdx.x] = m;
    nf[threadIdx.x] = (1.f - m) * NEGINF;
  }
  __syncthreads();
  const float* Stb = St + (size_t)b * LQ * LC + i;
  float v[64];
  float rmax = -3.4e38f;
#pragma unroll
  for (int j = 0; j < 64; ++j) {
    float s = Stb[(size_t)j * LC];
    s = fmaf(s, mk[j], nf[j]);
    v[j] = s;
    rmax = fmaxf(rmax, s);
  }
  float rsum = 0.f;
#pragma unroll
  for (int j = 0; j < 64; ++j) {
    float e = __expf(v[j] - rmax);
    v[j] = e;
    rsum += e;
  }
  float rinv = 1.f / rsum;
  int tile = i >> 7, ii = i & 127;
  float* dst = S1B + ((size_t)(b * (LC / 128) + tile) * LQ) * 128 + ii;
#pragma unroll
  for (int j = 0; j < 64; ++j) dst[j * 128] = v[j] * rinv;
}

// K4b: A = S1@Qt, Bm = S1@T; write out channels [C, A, C*A, C*Bm] transposed
// grid (LC/128, B); thread tile 4i x 8d; d processed in halves
__global__ __launch_bounds__(256) void k4b_out(const float* __restrict__ S1B,
                                               const float* __restrict__ Qt,
                                               const float* __restrict__ T,
                                               const float* __restrict__ C,
                                               float* __restrict__ out) {
  __shared__ float S1L[64][128];
  __shared__ float QtL[64][64];
  __shared__ float TL[64][64];
  int b = blockIdx.y;
  int tile = blockIdx.x;
  int i0 = tile * 128;
  int t = threadIdx.x;
  const float* s1src = S1B + (size_t)(b * (LC / 128) + tile) * LQ * 128;
  for (int k = t; k < LQ * 128; k += 256) ((float*)S1L)[k] = s1src[k];
  int ig = t & 31, dg = t >> 5;
  const float* Cb = C + (size_t)b * DD * LC + i0;
  float* outb = out + (size_t)b * (4 * DD) * LC + i0;
  for (int h = 0; h < 2; ++h) {
    __syncthreads();
    for (int k = t; k < LQ * 64; k += 256) {
      int j = k >> 6, dd = k & 63;
      QtL[j][dd] = Qt[((size_t)b * LQ + j) * DD + h * 64 + dd];
      TL[j][dd] = T[((size_t)b * LQ + j) * DD + h * 64 + dd];
    }
    __syncthreads();
    float accA[4][8] = {}, accB[4][8] = {};
#pragma unroll 4
    for (int j = 0; j < LQ; ++j) {
      float4 s4 = *(const float4*)&S1L[j][ig * 4];
      float sv[4] = {s4.x, s4.y, s4.z, s4.w};
      float qv[8], tv[8];
      *(float4*)&qv[0] = *(const float4*)&QtL[j][dg * 8];
      *(float4*)&qv[4] = *(const float4*)&QtL[j][dg * 8 + 4];
      *(float4*)&tv[0] = *(const float4*)&TL[j][dg * 8];
      *(float4*)&tv[4] = *(const float4*)&TL[j][dg * 8 + 4];
#pragma unroll
      for (int ii = 0; ii < 4; ++ii)
#pragma unroll
        for (int dd = 0; dd < 8; ++dd) {
          accA[ii][dd] = fmaf(sv[ii], qv[dd], accA[ii][dd]);
          accB[ii][dd] = fmaf(sv[ii], tv[dd], accB[ii][dd]);
        }
    }
#pragma unroll
    for (int dd = 0; dd < 8; ++dd) {
      int d = h * 64 + dg * 8 + dd;
      float4 c4 = *(const float4*)&Cb[(size_t)d * LC + ig * 4];
      float cv[4] = {c4.x, c4.y, c4.z, c4.w};
      float4 oA = make_float4(accA[0][dd], accA[1][dd], accA[2][dd], accA[3][dd]);
      float4 oCA = make_float4(cv[0] * accA[0][dd], cv[1] * accA[1][dd],
                               cv[2] * accA[2][dd], cv[3] * accA[3][dd]);
      float4 oCB = make_float4(cv[0] * accB[0][dd], cv[1] * accB[1][dd],
                               cv[2] * accB[2][dd], cv[3] * accB[3][dd]);
      *(float4*)&outb[(size_t)d * LC + ig * 4] = c4;
      *(float4*)&outb[(size_t)(DD + d) * LC + ig * 4] = oA;
      *(float4*)&outb[(size_t)(2 * DD + d) * LC + ig * 4] = oCA;
      *(float4*)&outb[(size_t)(3 * DD + d) * LC + ig * 4] = oCB;
    }
  }
}

extern "C" void kernel_launch(void* const* d_in, const int* in_sizes, int n_in,
                              void* d_out, int out_size, void* d_ws, size_t ws_size,
                              hipStream_t stream) {
  const float* C = (const float*)d_in[0];
  const float* Q = (const float*)d_in[1];
  const float* qmask = (const float*)d_in[2];
  const float* w = (const float*)d_in[3];
  float* out = (float*)d_out;
  int B = in_sizes[2] / LQ;

  float* ws = (float*)d_ws;
  size_t nSt = (size_t)B * LQ * LC;       // raw S, transposed [b][j][i]
  float* St = ws;
  float* S1B = St + nSt;                  // S1 tiled [b][tile][j][i']
  float* T = S1B + nSt;                   // B*64*128
  float* Qt = T + (size_t)B * LQ * DD;    // B*64*128
  float* M = Qt + (size_t)B * LQ * DD;
  float* Zi = M + (size_t)B * LQ;
  float* sqg = Zi + (size_t)B * LQ;

  k0_qt<<<B, 256, 0, stream>>>(Q, w, Qt, sqg);
  k1_S<<<dim3(LC / 128, B), 256, 0, stream>>>(C, Q, w, sqg, St);
  k2_stats<<<B * 16, 256, 0, stream>>>(St, M, Zi);
  hipMemsetAsync(T, 0, (size_t)B * LQ * DD * sizeof(float), stream);
  k3_T<<<dim3(LC / 128, B), 256, 0, stream>>>(St, C, M, Zi, T);
  k4a_S1<<<dim3(LC / 256, B), 256, 0, stream>>>(St, qmask, S1B);
  k4b_out<<<dim3(LC / 128, B), 256, 0, stream>>>(S1B, Qt, T, C, out);
}

// Round 2
// 111.831 us; speedup vs baseline: 1.3888x; 1.3888x over previous
//
#include <hip/hip_runtime.h>

#define LC 2048
#define DD 128
#define LQ 64
#define NPART 16
#define NEGINF (-1e30f)

__device__ inline unsigned fmap(float x) {
  unsigned u = __float_as_uint(x);
  return (u & 0x80000000u) ? ~u : (u | 0x80000000u);
}
__device__ inline float funmap(unsigned u) {
  return __uint_as_float((u & 0x80000000u) ? (u & 0x7fffffffu) : ~u);
}

// K0: transpose Q -> Qt[b][j][d]; sq[b][j] = Q^T w2; init Mu = 0 (mapped -inf floor)
__global__ __launch_bounds__(256) void k0_qt(const float* __restrict__ Q,
                                             const float* __restrict__ w,
                                             float* __restrict__ Qt,
                                             float* __restrict__ sqg,
                                             unsigned* __restrict__ Mu) {
  __shared__ float s[DD][LQ + 1];
  int b = blockIdx.x;
  const float* Qb = Q + (size_t)b * DD * LQ;
  for (int k = threadIdx.x; k < DD * LQ; k += 256)
    s[k >> 6][k & 63] = Qb[k];
  if (threadIdx.x < LQ) Mu[b * LQ + threadIdx.x] = 0u;
  __syncthreads();
  float* Qtb = Qt + (size_t)b * LQ * DD;
  for (int k = threadIdx.x; k < LQ * DD; k += 256) {
    int j = k >> 7, d = k & 127;
    Qtb[k] = s[d][j];
  }
  if (threadIdx.x < LQ) {
    int j = threadIdx.x;
    float acc = 0.f;
#pragma unroll
    for (int d = 0; d < DD; ++d) acc = fmaf(s[d][j], w[DD + d], acc);
    sqg[b * LQ + j] = acc;
  }
}

// K1: St[b][j][i] = sum_d C*w3*Q + sc[i] + sq[j]; atomicMax column max into Mu
__global__ __launch_bounds__(256) void k1_S(const float* __restrict__ C,
                                            const float* __restrict__ Q,
                                            const float* __restrict__ w,
                                            const float* __restrict__ sqg,
                                            float* __restrict__ St,
                                            unsigned* __restrict__ Mu) {
  __shared__ float Cs[32][128];
  __shared__ float Qw[32][64];
  __shared__ float sqs[64];
  __shared__ float w1s[128];
  int b = blockIdx.y;
  int i0 = blockIdx.x * 128;
  int t = threadIdx.x;
  const float* Cb = C + (size_t)b * DD * LC;
  const float* Qb = Q + (size_t)b * DD * LQ;
  if (t < 128) w1s[t] = w[t];
  else if (t < 192) sqs[t - 128] = sqg[b * LQ + (t - 128)];
  int ig = t & 31, jg = t >> 5;
  float acc[4][8] = {};
  float asc[4] = {};
  for (int dc = 0; dc < DD; dc += 32) {
    __syncthreads();
    for (int k = t; k < 32 * 128; k += 256) {
      int dd = k >> 7, ii = k & 127;
      Cs[dd][ii] = Cb[(size_t)(dc + dd) * LC + i0 + ii];
    }
    for (int k = t; k < 32 * 64; k += 256) {
      int dd = k >> 6, j = k & 63;
      Qw[dd][j] = Qb[(dd + dc) * LQ + j] * w[2 * DD + dc + dd];
    }
    __syncthreads();
#pragma unroll 8
    for (int dd = 0; dd < 32; ++dd) {
      float4 c4 = *(const float4*)&Cs[dd][ig * 4];
      float cv[4] = {c4.x, c4.y, c4.z, c4.w};
      float qv[8];
      *(float4*)&qv[0] = *(const float4*)&Qw[dd][jg * 8];
      *(float4*)&qv[4] = *(const float4*)&Qw[dd][jg * 8 + 4];
      float w1v = w1s[dc + dd];
#pragma unroll
      for (int ii = 0; ii < 4; ++ii) {
        asc[ii] = fmaf(cv[ii], w1v, asc[ii]);
#pragma unroll
        for (int jj = 0; jj < 8; ++jj)
          acc[ii][jj] = fmaf(cv[ii], qv[jj], acc[ii][jj]);
      }
    }
  }
  float* Stb = St + (size_t)b * LQ * LC + i0;
  float mx[8];
#pragma unroll
  for (int jj = 0; jj < 8; ++jj) {
    int j = jg * 8 + jj;
    float sqv = sqs[j];
    float4 o = make_float4(acc[0][jj] + asc[0] + sqv,
                           acc[1][jj] + asc[1] + sqv,
                           acc[2][jj] + asc[2] + sqv,
                           acc[3][jj] + asc[3] + sqv);
    *(float4*)&Stb[(size_t)j * LC + ig * 4] = o;
    mx[jj] = fmaxf(fmaxf(o.x, o.y), fmaxf(o.z, o.w));
  }
#pragma unroll
  for (int off = 1; off < 32; off <<= 1)
#pragma unroll
    for (int jj = 0; jj < 8; ++jj)
      mx[jj] = fmaxf(mx[jj], __shfl_xor(mx[jj], off, 64));
  if ((t & 31) == 0) {
#pragma unroll
    for (int jj = 0; jj < 8; ++jj)
      atomicMax(&Mu[b * LQ + jg * 8 + jj], fmap(mx[jj]));
  }
}

// K3: partial Tu_part[p][b][j][d] = sum_{i in chunk} exp(St-M) * C; Z_part too.
__global__ __launch_bounds__(256) void k3_T(const float* __restrict__ St,
                                            const float* __restrict__ C,
                                            const unsigned* __restrict__ Mu,
                                            float* __restrict__ Tu_part,
                                            float* __restrict__ Z_part,
                                            int B) {
  __shared__ float Es[128][64];
  __shared__ float Cs[128][64];
  __shared__ float red[4][64];
  int b = blockIdx.y;
  int bx = blockIdx.x;
  int i0 = bx * 128;
  int t = threadIdx.x;
  {
    int j = t & 63, ig = t >> 6;
    float mj = funmap(Mu[b * LQ + j]);
    const float* col = St + ((size_t)b * LQ + j) * LC + i0 + ig * 32;
    float zp = 0.f;
#pragma unroll
    for (int k4 = 0; k4 < 8; ++k4) {
      float4 v = *(const float4*)&col[k4 * 4];
      float e0 = __expf(v.x - mj), e1 = __expf(v.y - mj);
      float e2 = __expf(v.z - mj), e3 = __expf(v.w - mj);
      Es[ig * 32 + k4 * 4 + 0][j] = e0;
      Es[ig * 32 + k4 * 4 + 1][j] = e1;
      Es[ig * 32 + k4 * 4 + 2][j] = e2;
      Es[ig * 32 + k4 * 4 + 3][j] = e3;
      zp += e0 + e1 + e2 + e3;
    }
    red[ig][j] = zp;
  }
  __syncthreads();
  if (t < 64)
    Z_part[((size_t)bx * B + b) * LQ + t] =
        red[0][t] + red[1][t] + red[2][t] + red[3][t];
  int jg = t >> 4, dg = t & 15;
  const float* Cb = C + (size_t)b * DD * LC + i0;
  float* Tp = Tu_part + ((size_t)bx * B + b) * LQ * DD;
  for (int h = 0; h < 2; ++h) {
    __syncthreads();
    {
      int dd = t & 63, ig = t >> 6;
      const float* src = Cb + (size_t)(h * 64 + dd) * LC + ig * 32;
#pragma unroll
      for (int k4 = 0; k4 < 8; ++k4) {
        float4 v = *(const float4*)&src[k4 * 4];
        Cs[ig * 32 + k4 * 4 + 0][dd] = v.x;
        Cs[ig * 32 + k4 * 4 + 1][dd] = v.y;
        Cs[ig * 32 + k4 * 4 + 2][dd] = v.z;
        Cs[ig * 32 + k4 * 4 + 3][dd] = v.w;
      }
    }
    __syncthreads();
    float a[4][4] = {};
    for (int ii = 0; ii < 128; ++ii) {
      float4 e4 = *(const float4*)&Es[ii][jg * 4];
      float4 c4 = *(const float4*)&Cs[ii][dg * 4];
      float ev[4] = {e4.x, e4.y, e4.z, e4.w};
      float cv[4] = {c4.x, c4.y, c4.z, c4.w};
#pragma unroll
      for (int jj = 0; jj < 4; ++jj)
#pragma unroll
        for (int kk = 0; kk < 4; ++kk)
          a[jj][kk] = fmaf(ev[jj], cv[kk], a[jj][kk]);
    }
#pragma unroll
    for (int jj = 0; jj < 4; ++jj)
      *(float4*)&Tp[(size_t)(jg * 4 + jj) * DD + h * 64 + dg * 4] =
          make_float4(a[jj][0], a[jj][1], a[jj][2], a[jj][3]);
  }
}

// K3b: Tu = sum_p Tu_part; Zi = 1/sum_p Z_part. grid B.
__global__ __launch_bounds__(256) void k3b_red(const float* __restrict__ Tu_part,
                                               const float* __restrict__ Z_part,
                                               float* __restrict__ Tu,
                                               float* __restrict__ Zi,
                                               int B) {
  int b = blockIdx.x;
  int t = threadIdx.x;
#pragma unroll
  for (int k = 0; k < 8; ++k) {
    int f = t + k * 256;
    float4 acc = make_float4(0.f, 0.f, 0.f, 0.f);
#pragma unroll
    for (int p = 0; p < NPART; ++p) {
      float4 v = ((const float4*)&Tu_part[((size_t)p * B + b) * LQ * DD])[f];
      acc.x += v.x; acc.y += v.y; acc.z += v.z; acc.w += v.w;
    }
    ((float4*)&Tu[(size_t)b * LQ * DD])[f] = acc;
  }
  if (t < LQ) {
    float s = 0.f;
#pragma unroll
    for (int p = 0; p < NPART; ++p) s += Z_part[((size_t)p * B + b) * LQ + t];
    Zi[b * LQ + t] = 1.f / s;
  }
}

// K4: fused row-softmax (masked) + A = S1@Qt, Bm = S1@(Zi*Tu); write 4 channels
__global__ __launch_bounds__(256) void k4_out(const float* __restrict__ St,
                                              const float* __restrict__ qmask,
                                              const float* __restrict__ Qt,
                                              const float* __restrict__ Tu,
                                              const float* __restrict__ Zi,
                                              const float* __restrict__ C,
                                              float* __restrict__ out) {
  __shared__ float S1L[64][132];
  __shared__ float QtL[64][64];
  __shared__ float TL[64][64];
  __shared__ float mk[64], nf[64];
  __shared__ float red[4][128];
  int b = blockIdx.y;
  int i0 = blockIdx.x * 128;
  int t = threadIdx.x;
  if (t < 64) {
    float m = qmask[b * LQ + t];
    mk[t] = m;
    nf[t] = (1.f - m) * NEGINF;
  }
  __syncthreads();
  const float* Stb = St + (size_t)b * LQ * LC + i0;
  for (int k = t; k < 64 * 128; k += 256) {
    int j = k >> 7, ii = k & 127;
    float raw = Stb[(size_t)j * LC + ii];
    S1L[j][ii] = fmaf(raw, mk[j], nf[j]);
  }
  __syncthreads();
  // row softmax: row r, j-half hf
  int r = t & 127, hf = t >> 7;
  float vals[32];
  float pm = -3.4e38f;
#pragma unroll
  for (int jj = 0; jj < 32; ++jj) {
    float v = S1L[hf * 32 + jj][r];
    vals[jj] = v;
    pm = fmaxf(pm, v);
  }
  float ps = 0.f;
#pragma unroll
  for (int jj = 0; jj < 32; ++jj) {
    float e = __expf(vals[jj] - pm);
    vals[jj] = e;
    ps += e;
  }
  red[hf][r] = pm;
  red[2 + hf][r] = ps;
  __syncthreads();
  {
    float m0 = red[0][r], m1 = red[1][r];
    float gm = fmaxf(m0, m1);
    float gs = red[2][r] * __expf(m0 - gm) + red[3][r] * __expf(m1 - gm);
    float sc = __expf((hf ? m1 : m0) - gm) / gs;
#pragma unroll
    for (int jj = 0; jj < 32; ++jj) S1L[hf * 32 + jj][r] = vals[jj] * sc;
  }
  int ig = t & 31, dg = t >> 5;
  const float* Cb = C + (size_t)b * DD * LC + i0;
  float* outb = out + (size_t)b * (4 * DD) * LC + i0;
  for (int h = 0; h < 2; ++h) {
    __syncthreads();
    for (int k = t; k < LQ * 64; k += 256) {
      int j = k >> 6, dd = k & 63;
      float zj = Zi[b * LQ + j];
      QtL[j][dd] = Qt[((size_t)b * LQ + j) * DD + h * 64 + dd];
      TL[j][dd] = Tu[((size_t)b * LQ + j) * DD + h * 64 + dd] * zj;
    }
    __syncthreads();
    float accA[4][8] = {}, accB[4][8] = {};
#pragma unroll 4
    for (int j = 0; j < LQ; ++j) {
      float4 s4 = *(const float4*)&S1L[j][ig * 4];
      float sv[4] = {s4.x, s4.y, s4.z, s4.w};
      float qv[8], tv[8];
      *(float4*)&qv[0] = *(const float4*)&QtL[j][dg * 8];
      *(float4*)&qv[4] = *(const float4*)&QtL[j][dg * 8 + 4];
      *(float4*)&tv[0] = *(const float4*)&TL[j][dg * 8];
      *(float4*)&tv[4] = *(const float4*)&TL[j][dg * 8 + 4];
#pragma unroll
      for (int ii = 0; ii < 4; ++ii)
#pragma unroll
        for (int dd = 0; dd < 8; ++dd) {
          accA[ii][dd] = fmaf(sv[ii], qv[dd], accA[ii][dd]);
          accB[ii][dd] = fmaf(sv[ii], tv[dd], accB[ii][dd]);
        }
    }
#pragma unroll
    for (int dd = 0; dd < 8; ++dd) {
      int d = h * 64 + dg * 8 + dd;
      float4 c4 = *(const float4*)&Cb[(size_t)d * LC + ig * 4];
      float cv[4] = {c4.x, c4.y, c4.z, c4.w};
      float4 oA = make_float4(accA[0][dd], accA[1][dd], accA[2][dd], accA[3][dd]);
      float4 oCA = make_float4(cv[0] * accA[0][dd], cv[1] * accA[1][dd],
                               cv[2] * accA[2][dd], cv[3] * accA[3][dd]);
      float4 oCB = make_float4(cv[0] * accB[0][dd], cv[1] * accB[1][dd],
                               cv[2] * accB[2][dd], cv[3] * accB[3][dd]);
      *(float4*)&outb[(size_t)d * LC + ig * 4] = c4;
      *(float4*)&outb[(size_t)(DD + d) * LC + ig * 4] = oA;
      *(float4*)&outb[(size_t)(2 * DD + d) * LC + ig * 4] = oCA;
      *(float4*)&outb[(size_t)(3 * DD + d) * LC + ig * 4] = oCB;
    }
  }
}

extern "C" void kernel_launch(void* const* d_in, const int* in_sizes, int n_in,
                              void* d_out, int out_size, void* d_ws, size_t ws_size,
                              hipStream_t stream) {
  const float* C = (const float*)d_in[0];
  const float* Q = (const float*)d_in[1];
  const float* qmask = (const float*)d_in[2];
  const float* w = (const float*)d_in[3];
  float* out = (float*)d_out;
  int B = in_sizes[2] / LQ;

  float* ws = (float*)d_ws;
  size_t nSt = (size_t)B * LQ * LC;
  float* St = ws;                               // B*64*2048
  float* Tu_part = St + nSt;                    // 16*B*64*128
  float* Tu = Tu_part + (size_t)NPART * B * LQ * DD;  // B*64*128
  float* Z_part = Tu + (size_t)B * LQ * DD;     // 16*B*64
  float* Zi = Z_part + (size_t)NPART * B * LQ;  // B*64
  float* Qt = Zi + (size_t)B * LQ;              // B*64*128
  float* sqg = Qt + (size_t)B * LQ * DD;        // B*64
  unsigned* Mu = (unsigned*)(sqg + (size_t)B * LQ);  // B*64

  k0_qt<<<B, 256, 0, stream>>>(Q, w, Qt, sqg, Mu);
  k1_S<<<dim3(LC / 128, B), 256, 0, stream>>>(C, Q, w, sqg, St, Mu);
  k3_T<<<dim3(NPART, B), 256, 0, stream>>>(St, C, Mu, Tu_part, Z_part, B);
  k3b_red<<<B, 256, 0, stream>>>(Tu_part, Z_part, Tu, Zi, B);
  k4_out<<<dim3(LC / 128, B), 256, 0, stream>>>(St, qmask, Qt, Tu, Zi, C, out);
}

// Round 3
// 96.798 us; speedup vs baseline: 1.6045x; 1.1553x over previous
//
#include <hip/hip_runtime.h>

#define LC 2048
#define DD 128
#define LQ 64
#define NPART 16

typedef unsigned short u16;
typedef unsigned int u32;
typedef __attribute__((ext_vector_type(8))) short bf16x8;
typedef __attribute__((ext_vector_type(4))) float f32x4;

__device__ inline u16 f2b(float f) {
  u32 u = __float_as_uint(f);
  u32 r = (u + 0x7fffu + ((u >> 16) & 1u)) >> 16;
  return (u16)r;
}
__device__ inline float b2f(u16 u) { return __uint_as_float(((u32)u) << 16); }
__device__ inline u32 pack2(float a, float b) {
  return (u32)f2b(a) | ((u32)f2b(b) << 16);
}

// K0: sq[b][j] = sum_d Q[b][d][j] * w2[d]
__global__ __launch_bounds__(64) void k0_sq(const float* __restrict__ Q,
                                            const float* __restrict__ w,
                                            float* __restrict__ sqg) {
  int b = blockIdx.x, j = threadIdx.x;
  const float* Qb = Q + (size_t)b * DD * LQ + j;
  float acc = 0.f;
#pragma unroll 16
  for (int d = 0; d < DD; ++d) acc = fmaf(Qb[d * LQ], w[DD + d], acc);
  sqg[b * LQ + j] = acc;
}

// K13: fused S-GEMM + exp + E write (bf16) + Z partial + T-partial GEMM
__global__ __launch_bounds__(256) void k13(const float* __restrict__ C,
                                           const float* __restrict__ Q,
                                           const float* __restrict__ w,
                                           const float* __restrict__ sqg,
                                           u16* __restrict__ Eg,
                                           float* __restrict__ Tu_part,
                                           float* __restrict__ Z_part, int B) {
  __shared__ float smem[17408];  // 69.6 KB: phase1 Cs1[32*128]+Qw[32*64] alias Es
  float* Cs1 = smem;             // [32][128]
  float* Qw = smem + 4096;       // [32][64]
  float* Es = smem;              // [128][68]
  float* Cs2 = smem + 8704;      // [128][68]
  __shared__ float sqs[64], w1s[128], red[4][64];
  int b = blockIdx.y, bx = blockIdx.x;
  int i0 = bx * 128, t = threadIdx.x;
  const float* Cb = C + (size_t)b * DD * LC;
  const float* Qb = Q + (size_t)b * DD * LQ;
  if (t < 128) w1s[t] = w[t];
  else if (t < 192) sqs[t - 128] = sqg[b * LQ + (t - 128)];
  int ig = t & 31, jg = t >> 5;
  float acc[4][8] = {};
  float asc[4] = {};
  for (int dc = 0; dc < DD; dc += 32) {
    __syncthreads();
    for (int k = t; k < 32 * 128; k += 256)
      Cs1[k] = Cb[(size_t)(dc + (k >> 7)) * LC + i0 + (k & 127)];
    for (int k = t; k < 32 * 64; k += 256)
      Qw[k] = Qb[((k >> 6) + dc) * LQ + (k & 63)] * w[2 * DD + dc + (k >> 6)];
    __syncthreads();
#pragma unroll 8
    for (int dd = 0; dd < 32; ++dd) {
      float4 c4 = *(const float4*)&Cs1[dd * 128 + ig * 4];
      float cv[4] = {c4.x, c4.y, c4.z, c4.w};
      float qv[8];
      *(float4*)&qv[0] = *(const float4*)&Qw[dd * 64 + jg * 8];
      *(float4*)&qv[4] = *(const float4*)&Qw[dd * 64 + jg * 8 + 4];
      float w1v = w1s[dc + dd];
#pragma unroll
      for (int ii = 0; ii < 4; ++ii) {
        asc[ii] = fmaf(cv[ii], w1v, asc[ii]);
#pragma unroll
        for (int jj = 0; jj < 8; ++jj)
          acc[ii][jj] = fmaf(cv[ii], qv[jj], acc[ii][jj]);
      }
    }
  }
  __syncthreads();  // all waves done with Cs1/Qw before Es overwrite
  u16* Egb = Eg + ((size_t)b * LC + i0) * LQ;
#pragma unroll
  for (int ii = 0; ii < 4; ++ii) {
    int i = ig * 4 + ii;
    float e[8];
#pragma unroll
    for (int jj = 0; jj < 8; ++jj)
      e[jj] = __expf(acc[ii][jj] + asc[ii] + sqs[jg * 8 + jj]);
    *(float4*)&Es[i * 68 + jg * 8] = make_float4(e[0], e[1], e[2], e[3]);
    *(float4*)&Es[i * 68 + jg * 8 + 4] = make_float4(e[4], e[5], e[6], e[7]);
    u32 pk[4] = {pack2(e[0], e[1]), pack2(e[2], e[3]), pack2(e[4], e[5]),
                 pack2(e[6], e[7])};
    *(uint4*)&Egb[(size_t)i * LQ + jg * 8] = *(uint4*)pk;
  }
  __syncthreads();
  {  // Z partials: per-j sum over this block's 128 i
    int jz = t & 63, qz = t >> 6;
    float z = 0.f;
#pragma unroll 8
    for (int i = qz * 32; i < qz * 32 + 32; ++i) z += Es[i * 68 + jz];
    red[qz][jz] = z;
  }
  __syncthreads();
  if (t < 64)
    Z_part[((size_t)bx * B + b) * LQ + t] =
        red[0][t] + red[1][t] + red[2][t] + red[3][t];
  // T-partial GEMM: Tp[j][d] = sum_i Es[i][j] * C[d][i]
  int jg2 = t >> 4, dg = t & 15;
  float* Tp = Tu_part + ((size_t)bx * B + b) * LQ * DD;
  for (int h = 0; h < 2; ++h) {
    __syncthreads();
    {
      int dd = t & 63, ig2 = t >> 6;
      const float* src = Cb + (size_t)(h * 64 + dd) * LC + i0 + ig2 * 32;
#pragma unroll
      for (int k4i = 0; k4i < 8; ++k4i) {
        float4 v = *(const float4*)&src[k4i * 4];
        Cs2[(ig2 * 32 + k4i * 4 + 0) * 68 + dd] = v.x;
        Cs2[(ig2 * 32 + k4i * 4 + 1) * 68 + dd] = v.y;
        Cs2[(ig2 * 32 + k4i * 4 + 2) * 68 + dd] = v.z;
        Cs2[(ig2 * 32 + k4i * 4 + 3) * 68 + dd] = v.w;
      }
    }
    __syncthreads();
    float a[4][4] = {};
    for (int ii = 0; ii < 128; ++ii) {
      float4 e4 = *(const float4*)&Es[ii * 68 + jg2 * 4];
      float4 c4 = *(const float4*)&Cs2[ii * 68 + dg * 4];
      float ev[4] = {e4.x, e4.y, e4.z, e4.w};
      float cv[4] = {c4.x, c4.y, c4.z, c4.w};
#pragma unroll
      for (int jj = 0; jj < 4; ++jj)
#pragma unroll
        for (int kk = 0; kk < 4; ++kk)
          a[jj][kk] = fmaf(ev[jj], cv[kk], a[jj][kk]);
    }
#pragma unroll
    for (int jj = 0; jj < 4; ++jj)
      *(float4*)&Tp[(size_t)(jg2 * 4 + jj) * DD + h * 64 + dg * 4] =
          make_float4(a[jj][0], a[jj][1], a[jj][2], a[jj][3]);
  }
}

// K3b: sum Tu partials, scale by Zi=1/sum(Z_part), write TzT[b][d][j] bf16
__global__ __launch_bounds__(256) void k3b(const float* __restrict__ Tu_part,
                                           const float* __restrict__ Z_part,
                                           u16* __restrict__ TzT, int B) {
  __shared__ float Tsm[16][68];
  __shared__ float ziL[64];
  int b = blockIdx.y, d0 = blockIdx.x * 16;
  int t = threadIdx.x;
  int dd = t & 15, jg = t >> 4;
  float acc[4] = {};
#pragma unroll
  for (int p = 0; p < NPART; ++p) {
    const float* src = Tu_part + ((size_t)p * B + b) * LQ * DD + d0 + dd;
#pragma unroll
    for (int jj = 0; jj < 4; ++jj) acc[jj] += src[(jg * 4 + jj) * DD];
  }
  if (t < 64) {
    float z = 0.f;
#pragma unroll
    for (int p = 0; p < NPART; ++p) z += Z_part[((size_t)p * B + b) * LQ + t];
    ziL[t] = 1.f / z;
  }
  *(float4*)&Tsm[dd][jg * 4] = make_float4(acc[0], acc[1], acc[2], acc[3]);
  __syncthreads();
  if (t < 128) {
    int d = t >> 3, seg = t & 7;
    u32 pk[4];
#pragma unroll
    for (int q = 0; q < 4; ++q) {
      int j = seg * 8 + q * 2;
      pk[q] = pack2(Tsm[d][j] * ziL[j], Tsm[d][j + 1] * ziL[j + 1]);
    }
    *(uint4*)&TzT[((size_t)b * DD + d0 + d) * LQ + seg * 8] = *(uint4*)pk;
  }
}

// K4: MFMA — A = S1@Qt, Bm = S1@Tz; out = [C, A, C*A, C*Bm]
__global__ __launch_bounds__(256) void k4(const u16* __restrict__ Eg,
                                          const float* __restrict__ qmask,
                                          const float* __restrict__ Q,
                                          const u16* __restrict__ TzT,
                                          const float* __restrict__ C,
                                          float* __restrict__ out) {
  __shared__ u16 S1L[128 * 72];
  __shared__ u16 QtL[128 * 72];
  __shared__ u16 TzL[128 * 72];
  __shared__ float mkL[64];
  int b = blockIdx.y, i0 = blockIdx.x * 128, t = threadIdx.x;
  if (t < 64) mkL[t] = qmask[b * LQ + t];
  __syncthreads();
  {
    int row = t >> 1, half = t & 1;
    // stage Qt^T (= Q natural [d][j]) and Tz^T as bf16
    const float* qsrc = Q + (size_t)b * DD * LQ + row * LQ + half * 32;
    u32 qpk[16];
#pragma unroll
    for (int q = 0; q < 16; ++q) qpk[q] = pack2(qsrc[2 * q], qsrc[2 * q + 1]);
#pragma unroll
    for (int q = 0; q < 4; ++q)
      *(uint4*)&QtL[row * 72 + half * 32 + q * 8] = *(uint4*)&qpk[q * 4];
    const u16* tsrc = TzT + ((size_t)b * DD + row) * LQ + half * 32;
#pragma unroll
    for (int q = 0; q < 4; ++q)
      *(uint4*)&TzL[row * 72 + half * 32 + q * 8] = *(const uint4*)&tsrc[q * 8];
    // row-softmax from E: masked, normalized
    const u16* esrc = Eg + ((size_t)b * LC + i0 + row) * LQ + half * 32;
    u16 lv[32];
#pragma unroll
    for (int q = 0; q < 4; ++q)
      *(uint4*)&lv[q * 8] = *(const uint4*)&esrc[q * 8];
    float ev[32], ps = 0.f;
#pragma unroll
    for (int q = 0; q < 32; ++q) {
      ev[q] = b2f(lv[q]) * mkL[half * 32 + q];
      ps += ev[q];
    }
    ps += __shfl_xor(ps, 1);
    float inv = 1.f / fmaxf(ps, 1e-30f);
    u32 opk[16];
#pragma unroll
    for (int q = 0; q < 16; ++q)
      opk[q] = pack2(ev[2 * q] * inv, ev[2 * q + 1] * inv);
#pragma unroll
    for (int q = 0; q < 4; ++q)
      *(uint4*)&S1L[row * 72 + half * 32 + q * 8] = *(uint4*)&opk[q * 4];
  }
  __syncthreads();
  int lane = t & 63, wv = t >> 6;
  int lr = lane & 15, kg = lane >> 4;
  bf16x8 Bf[2][2];
#pragma unroll
  for (int it = 0; it < 2; ++it)
#pragma unroll
    for (int ks = 0; ks < 2; ++ks)
      Bf[it][ks] =
          *(bf16x8*)&S1L[(wv * 32 + it * 16 + lr) * 72 + ks * 32 + kg * 8];
  const float* Cb = C + (size_t)b * DD * LC + i0;
  float* outb = out + (size_t)b * 4 * DD * LC + i0;
#pragma unroll
  for (int dt = 0; dt < 8; ++dt) {
    bf16x8 QA[2], TA[2];
#pragma unroll
    for (int ks = 0; ks < 2; ++ks) {
      QA[ks] = *(bf16x8*)&QtL[(dt * 16 + lr) * 72 + ks * 32 + kg * 8];
      TA[ks] = *(bf16x8*)&TzL[(dt * 16 + lr) * 72 + ks * 32 + kg * 8];
    }
#pragma unroll
    for (int it = 0; it < 2; ++it) {
      f32x4 accA = {0.f, 0.f, 0.f, 0.f}, accB = {0.f, 0.f, 0.f, 0.f};
      accA = __builtin_amdgcn_mfma_f32_16x16x32_bf16(QA[0], Bf[it][0], accA, 0, 0, 0);
      accA = __builtin_amdgcn_mfma_f32_16x16x32_bf16(QA[1], Bf[it][1], accA, 0, 0, 0);
      accB = __builtin_amdgcn_mfma_f32_16x16x32_bf16(TA[0], Bf[it][0], accB, 0, 0, 0);
      accB = __builtin_amdgcn_mfma_f32_16x16x32_bf16(TA[1], Bf[it][1], accB, 0, 0, 0);
      int ii = wv * 32 + it * 16 + lr;
#pragma unroll
      for (int r = 0; r < 4; ++r) {
        int d = dt * 16 + kg * 4 + r;
        float c = Cb[(size_t)d * LC + ii];
        float a = accA[r], bm = accB[r];
        outb[(size_t)d * LC + ii] = c;
        outb[(size_t)(DD + d) * LC + ii] = a;
        outb[(size_t)(2 * DD + d) * LC + ii] = c * a;
        outb[(size_t)(3 * DD + d) * LC + ii] = c * bm;
      }
    }
  }
}

extern "C" void kernel_launch(void* const* d_in, const int* in_sizes, int n_in,
                              void* d_out, int out_size, void* d_ws, size_t ws_size,
                              hipStream_t stream) {
  const float* C = (const float*)d_in[0];
  const float* Q = (const float*)d_in[1];
  const float* qmask = (const float*)d_in[2];
  const float* w = (const float*)d_in[3];
  float* out = (float*)d_out;
  int B = in_sizes[2] / LQ;

  char* p = (char*)d_ws;
  u16* Eg = (u16*)p;            p += (size_t)B * LC * LQ * 2;
  u16* TzT = (u16*)p;           p += (size_t)B * DD * LQ * 2;
  float* Tu_part = (float*)p;   p += (size_t)NPART * B * LQ * DD * 4;
  float* Z_part = (float*)p;    p += (size_t)NPART * B * LQ * 4;
  float* sqg = (float*)p;

  k0_sq<<<B, 64, 0, stream>>>(Q, w, sqg);
  k13<<<dim3(NPART, B), 256, 0, stream>>>(C, Q, w, sqg, Eg, Tu_part, Z_part, B);
  k3b<<<dim3(DD / 16, B), 256, 0, stream>>>(Tu_part, Z_part, TzT, B);
  k4<<<dim3(LC / 128, B), 256, 0, stream>>>(Eg, qmask, Q, TzT, C, out);
}

// Round 4
// 76.906 us; speedup vs baseline: 2.0195x; 1.2587x over previous
//
#include <hip/hip_runtime.h>

#define LC 2048
#define DD 128
#define LQ 64
#define NPART 16
#define PAD 136

typedef unsigned short u16;
typedef unsigned int u32;
typedef __attribute__((ext_vector_type(8))) short bf16x8;
typedef __attribute__((ext_vector_type(4))) float f32x4;

__device__ inline u16 f2b(float f) {
  u32 u = __float_as_uint(f);
  u32 r = (u + 0x7fffu + ((u >> 16) & 1u)) >> 16;
  return (u16)r;
}
__device__ inline float b2f(u16 u) { return __uint_as_float(((u32)u) << 16); }
__device__ inline u32 pack2(float a, float b) {
  return (u32)f2b(a) | ((u32)f2b(b) << 16);
}

// K0: sq[b][j] = sum_d Q[b][d][j] * w2[d]
__global__ __launch_bounds__(64) void k0_sq(const float* __restrict__ Q,
                                            const float* __restrict__ w,
                                            float* __restrict__ sqg) {
  int b = blockIdx.x, j = threadIdx.x;
  const float* Qb = Q + (size_t)b * DD * LQ + j;
  float acc = 0.f;
#pragma unroll 16
  for (int d = 0; d < DD; ++d) acc = fmaf(Qb[d * LQ], w[DD + d], acc);
  sqg[b * LQ + j] = acc;
}

// K13: MFMA S-GEMM + exp + Eg write + Z partial + MFMA T-partial GEMM
__global__ __launch_bounds__(256) void k13(const float* __restrict__ C,
                                           const float* __restrict__ Q,
                                           const float* __restrict__ w,
                                           const float* __restrict__ sqg,
                                           u16* __restrict__ Eg,
                                           float* __restrict__ Tu_part,
                                           float* __restrict__ Z_part, int B) {
  __shared__ u16 ldsA[128 * PAD];  // phase1: C^T[i][d]; phase3: Cnat[d][i]
  __shared__ u16 ldsB[64 * PAD];   // phase1: Qw^T[j][d]; phase3: E^T[j][i]
  __shared__ float scL[128];
  __shared__ float sqs[64];
  int b = blockIdx.y, bx = blockIdx.x;
  int i0 = bx * 128, t = threadIdx.x;
  const float* Cb = C + (size_t)b * DD * LC;
  const float* Qb = Q + (size_t)b * DD * LQ;
  if (t < 64) sqs[t] = sqg[b * LQ + t];
  // --- phase 1 staging: C^T (bf16, transposed) + sc partial (fp32) ---
  int i_st = t & 127, dh = t >> 7;
  float scp = 0.f;
  {
    const float* Cp = Cb + (size_t)dh * 64 * LC + i0 + i_st;
#pragma unroll
    for (int dp = 0; dp < 32; ++dp) {
      int d = dh * 64 + 2 * dp;
      float c0 = Cp[(size_t)(2 * dp) * LC];
      float c1 = Cp[(size_t)(2 * dp + 1) * LC];
      scp = fmaf(c0, w[d], fmaf(c1, w[d + 1], scp));
      *(u32*)&ldsA[i_st * PAD + d] = pack2(c0, c1);
    }
    if (dh == 0) scL[i_st] = scp;
  }
  // Qw^T staging
  {
    int j = t & 63, dg = t >> 6;
    const float* Qp = Qb + j;
#pragma unroll
    for (int dp = 0; dp < 16; ++dp) {
      int d = dg * 32 + 2 * dp;
      float q0 = Qp[(size_t)d * LQ] * w[2 * DD + d];
      float q1 = Qp[(size_t)(d + 1) * LQ] * w[2 * DD + d + 1];
      *(u32*)&ldsB[j * PAD + d] = pack2(q0, q1);
    }
  }
  __syncthreads();
  if (dh == 1) scL[i_st] += scp;  // single writer per i; read after next barrier
  // --- phase 2: S-GEMM (D[i][j] = sum_d C^T[i][d]*Qw^T[j][d]) ---
  int lane = t & 63, wv = t >> 6;
  int lr = lane & 15, kg = lane >> 4;
  f32x4 acc[2][4];
#pragma unroll
  for (int mt = 0; mt < 2; ++mt)
#pragma unroll
    for (int nt = 0; nt < 4; ++nt) acc[mt][nt] = (f32x4){0.f, 0.f, 0.f, 0.f};
#pragma unroll
  for (int ks = 0; ks < 4; ++ks) {
    bf16x8 af[2], bf[4];
#pragma unroll
    for (int mt = 0; mt < 2; ++mt)
      af[mt] = *(bf16x8*)&ldsA[((wv * 2 + mt) * 16 + lr) * PAD + ks * 32 + kg * 8];
#pragma unroll
    for (int nt = 0; nt < 4; ++nt)
      bf[nt] = *(bf16x8*)&ldsB[(nt * 16 + lr) * PAD + ks * 32 + kg * 8];
#pragma unroll
    for (int mt = 0; mt < 2; ++mt)
#pragma unroll
      for (int nt = 0; nt < 4; ++nt)
        acc[mt][nt] = __builtin_amdgcn_mfma_f32_16x16x32_bf16(af[mt], bf[nt],
                                                              acc[mt][nt], 0, 0, 0);
  }
  __syncthreads();  // all MFMA reads of ldsA/ldsB done; scL final
  // --- epilogue: e = exp(S + sc + sq) -> E^T[j][i] (overlays ldsB) ---
#pragma unroll
  for (int mt = 0; mt < 2; ++mt) {
    int ib = (wv * 2 + mt) * 16 + kg * 4;
#pragma unroll
    for (int nt = 0; nt < 4; ++nt) {
      int j = nt * 16 + lr;
      float sqv = sqs[j];
      float e0 = __expf(acc[mt][nt][0] + scL[ib + 0] + sqv);
      float e1 = __expf(acc[mt][nt][1] + scL[ib + 1] + sqv);
      float e2 = __expf(acc[mt][nt][2] + scL[ib + 2] + sqv);
      float e3 = __expf(acc[mt][nt][3] + scL[ib + 3] + sqv);
      u32 pk[2] = {pack2(e0, e1), pack2(e2, e3)};
      *(uint2*)&ldsB[j * PAD + ib] = *(uint2*)pk;
    }
  }
  // --- Cnat staging: C[d][i] bf16 (overlays ldsA) ---
  {
    int d = t >> 1, half = t & 1;
    const float* src = Cb + (size_t)d * LC + i0 + half * 64;
#pragma unroll
    for (int ip = 0; ip < 16; ++ip) {
      float4 v = *(const float4*)&src[ip * 4];
      u32 pk[2] = {pack2(v.x, v.y), pack2(v.z, v.w)};
      *(uint2*)&ldsA[d * PAD + half * 64 + ip * 4] = *(uint2*)pk;
    }
  }
  __syncthreads();
  // --- phase 3 ---
  // Z[j] over this block's 128 i (wave 0 only; read-only on ldsB)
  if (t < 64) {
    const u32* row = (const u32*)&ldsB[t * PAD];
    float z = 0.f;
#pragma unroll
    for (int q = 0; q < 64; ++q) {
      u32 v = row[q];
      z += b2f((u16)v) + b2f((u16)(v >> 16));
    }
    Z_part[((size_t)bx * B + b) * LQ + t] = z;
  }
  // Eg dump: transpose E^T -> Eg[i][j] (coalesced 64B per thread)
  {
    int i = t >> 1, half = t & 1;
    u32 opk[16];
#pragma unroll
    for (int q = 0; q < 16; ++q) {
      u16 a0 = ldsB[(half * 32 + 2 * q) * PAD + i];
      u16 a1 = ldsB[(half * 32 + 2 * q + 1) * PAD + i];
      opk[q] = (u32)a0 | ((u32)a1 << 16);
    }
    u16* dst = Eg + ((size_t)b * LC + i0 + i) * LQ + half * 32;
#pragma unroll
    for (int q = 0; q < 4; ++q) *(uint4*)&dst[q * 8] = *(uint4*)&opk[q * 4];
  }
  // T-GEMM: Tp[j][d] = sum_i E[i][j]*C[d][i]  (A=Cnat rows d, B=E^T rows j)
  f32x4 tacc[2][4];
#pragma unroll
  for (int mt = 0; mt < 2; ++mt)
#pragma unroll
    for (int nt = 0; nt < 4; ++nt) tacc[mt][nt] = (f32x4){0.f, 0.f, 0.f, 0.f};
#pragma unroll
  for (int ks = 0; ks < 4; ++ks) {
    bf16x8 af[2], bf[4];
#pragma unroll
    for (int mt = 0; mt < 2; ++mt)
      af[mt] = *(bf16x8*)&ldsA[((wv * 2 + mt) * 16 + lr) * PAD + ks * 32 + kg * 8];
#pragma unroll
    for (int nt = 0; nt < 4; ++nt)
      bf[nt] = *(bf16x8*)&ldsB[(nt * 16 + lr) * PAD + ks * 32 + kg * 8];
#pragma unroll
    for (int mt = 0; mt < 2; ++mt)
#pragma unroll
      for (int nt = 0; nt < 4; ++nt)
        tacc[mt][nt] = __builtin_amdgcn_mfma_f32_16x16x32_bf16(af[mt], bf[nt],
                                                               tacc[mt][nt], 0, 0, 0);
  }
  float* Tp = Tu_part + ((size_t)bx * B + b) * LQ * DD;
#pragma unroll
  for (int mt = 0; mt < 2; ++mt)
#pragma unroll
    for (int nt = 0; nt < 4; ++nt) {
      int j = nt * 16 + lr;
      int db = (wv * 2 + mt) * 16 + kg * 4;
      *(f32x4*)&Tp[(size_t)j * DD + db] = tacc[mt][nt];
    }
}

// K3b: sum Tu partials, scale by Zi=1/sum(Z_part), write TzT[b][d][j] bf16
__global__ __launch_bounds__(256) void k3b(const float* __restrict__ Tu_part,
                                           const float* __restrict__ Z_part,
                                           u16* __restrict__ TzT, int B) {
  __shared__ float Tsm[16][68];
  __shared__ float ziL[64];
  int b = blockIdx.y, d0 = blockIdx.x * 16;
  int t = threadIdx.x;
  int dd = t & 15, jg = t >> 4;
  float acc[4] = {};
#pragma unroll
  for (int p = 0; p < NPART; ++p) {
    const float* src = Tu_part + ((size_t)p * B + b) * LQ * DD + d0 + dd;
#pragma unroll
    for (int jj = 0; jj < 4; ++jj) acc[jj] += src[(jg * 4 + jj) * DD];
  }
  if (t < 64) {
    float z = 0.f;
#pragma unroll
    for (int p = 0; p < NPART; ++p) z += Z_part[((size_t)p * B + b) * LQ + t];
    ziL[t] = 1.f / z;
  }
  *(float4*)&Tsm[dd][jg * 4] = make_float4(acc[0], acc[1], acc[2], acc[3]);
  __syncthreads();
  if (t < 128) {
    int d = t >> 3, seg = t & 7;
    u32 pk[4];
#pragma unroll
    for (int q = 0; q < 4; ++q) {
      int j = seg * 8 + q * 2;
      pk[q] = pack2(Tsm[d][j] * ziL[j], Tsm[d][j + 1] * ziL[j + 1]);
    }
    *(uint4*)&TzT[((size_t)b * DD + d0 + d) * LQ + seg * 8] = *(uint4*)pk;
  }
}

// K4: MFMA — A = S1@Qt, Bm = S1@Tz; out = [C, A, C*A, C*Bm]
__global__ __launch_bounds__(256) void k4(const u16* __restrict__ Eg,
                                          const float* __restrict__ qmask,
                                          const float* __restrict__ Q,
                                          const u16* __restrict__ TzT,
                                          const float* __restrict__ C,
                                          float* __restrict__ out) {
  __shared__ u16 S1L[128 * 72];
  __shared__ u16 QtL[128 * 72];
  __shared__ u16 TzL[128 * 72];
  __shared__ float mkL[64];
  int b = blockIdx.y, i0 = blockIdx.x * 128, t = threadIdx.x;
  if (t < 64) mkL[t] = qmask[b * LQ + t];
  __syncthreads();
  {
    int row = t >> 1, half = t & 1;
    const float* qsrc = Q + (size_t)b * DD * LQ + row * LQ + half * 32;
    u32 qpk[16];
#pragma unroll
    for (int q = 0; q < 16; ++q) qpk[q] = pack2(qsrc[2 * q], qsrc[2 * q + 1]);
#pragma unroll
    for (int q = 0; q < 4; ++q)
      *(uint4*)&QtL[row * 72 + half * 32 + q * 8] = *(uint4*)&qpk[q * 4];
    const u16* tsrc = TzT + ((size_t)b * DD + row) * LQ + half * 32;
#pragma unroll
    for (int q = 0; q < 4; ++q)
      *(uint4*)&TzL[row * 72 + half * 32 + q * 8] = *(const uint4*)&tsrc[q * 8];
    const u16* esrc = Eg + ((size_t)b * LC + i0 + row) * LQ + half * 32;
    u16 lv[32];
#pragma unroll
    for (int q = 0; q < 4; ++q)
      *(uint4*)&lv[q * 8] = *(const uint4*)&esrc[q * 8];
    float ev[32], ps = 0.f;
#pragma unroll
    for (int q = 0; q < 32; ++q) {
      ev[q] = b2f(lv[q]) * mkL[half * 32 + q];
      ps += ev[q];
    }
    ps += __shfl_xor(ps, 1);
    float inv = 1.f / fmaxf(ps, 1e-30f);
    u32 opk[16];
#pragma unroll
    for (int q = 0; q < 16; ++q)
      opk[q] = pack2(ev[2 * q] * inv, ev[2 * q + 1] * inv);
#pragma unroll
    for (int q = 0; q < 4; ++q)
      *(uint4*)&S1L[row * 72 + half * 32 + q * 8] = *(uint4*)&opk[q * 4];
  }
  __syncthreads();
  int lane = t & 63, wv = t >> 6;
  int lr = lane & 15, kg = lane >> 4;
  bf16x8 Bf[2][2];
#pragma unroll
  for (int it = 0; it < 2; ++it)
#pragma unroll
    for (int ks = 0; ks < 2; ++ks)
      Bf[it][ks] =
          *(bf16x8*)&S1L[(wv * 32 + it * 16 + lr) * 72 + ks * 32 + kg * 8];
  const float* Cb = C + (size_t)b * DD * LC + i0;
  float* outb = out + (size_t)b * 4 * DD * LC + i0;
#pragma unroll
  for (int dt = 0; dt < 8; ++dt) {
    bf16x8 QA[2], TA[2];
#pragma unroll
    for (int ks = 0; ks < 2; ++ks) {
      QA[ks] = *(bf16x8*)&QtL[(dt * 16 + lr) * 72 + ks * 32 + kg * 8];
      TA[ks] = *(bf16x8*)&TzL[(dt * 16 + lr) * 72 + ks * 32 + kg * 8];
    }
#pragma unroll
    for (int it = 0; it < 2; ++it) {
      f32x4 accA = {0.f, 0.f, 0.f, 0.f}, accB = {0.f, 0.f, 0.f, 0.f};
      accA = __builtin_amdgcn_mfma_f32_16x16x32_bf16(QA[0], Bf[it][0], accA, 0, 0, 0);
      accA = __builtin_amdgcn_mfma_f32_16x16x32_bf16(QA[1], Bf[it][1], accA, 0, 0, 0);
      accB = __builtin_amdgcn_mfma_f32_16x16x32_bf16(TA[0], Bf[it][0], accB, 0, 0, 0);
      accB = __builtin_amdgcn_mfma_f32_16x16x32_bf16(TA[1], Bf[it][1], accB, 0, 0, 0);
      int ii = wv * 32 + it * 16 + lr;
#pragma unroll
      for (int r = 0; r < 4; ++r) {
        int d = dt * 16 + kg * 4 + r;
        float c = Cb[(size_t)d * LC + ii];
        float a = accA[r], bm = accB[r];
        outb[(size_t)d * LC + ii] = c;
        outb[(size_t)(DD + d) * LC + ii] = a;
        outb[(size_t)(2 * DD + d) * LC + ii] = c * a;
        outb[(size_t)(3 * DD + d) * LC + ii] = c * bm;
      }
    }
  }
}

extern "C" void kernel_launch(void* const* d_in, const int* in_sizes, int n_in,
                              void* d_out, int out_size, void* d_ws, size_t ws_size,
                              hipStream_t stream) {
  const float* C = (const float*)d_in[0];
  const float* Q = (const float*)d_in[1];
  const float* qmask = (const float*)d_in[2];
  const float* w = (const float*)d_in[3];
  float* out = (float*)d_out;
  int B = in_sizes[2] / LQ;

  char* p = (char*)d_ws;
  u16* Eg = (u16*)p;            p += (size_t)B * LC * LQ * 2;
  u16* TzT = (u16*)p;           p += (size_t)B * DD * LQ * 2;
  float* Tu_part = (float*)p;   p += (size_t)NPART * B * LQ * DD * 4;
  float* Z_part = (float*)p;    p += (size_t)NPART * B * LQ * 4;
  float* sqg = (float*)p;

  k0_sq<<<B, 64, 0, stream>>>(Q, w, sqg);
  k13<<<dim3(NPART, B), 256, 0, stream>>>(C, Q, w, sqg, Eg, Tu_part, Z_part, B);
  k3b<<<dim3(DD / 16, B), 256, 0, stream>>>(Tu_part, Z_part, TzT, B);
  k4<<<dim3(LC / 128, B), 256, 0, stream>>>(Eg, qmask, Q, TzT, C, out);
}

// Round 5
// 71.580 us; speedup vs baseline: 2.1698x; 1.0744x over previous
//
#include <hip/hip_runtime.h>

#define LC 2048
#define DD 128
#define LQ 64
#define NPART 16
#define PAD 136

typedef unsigned short u16;
typedef unsigned int u32;
typedef __attribute__((ext_vector_type(8))) short bf16x8;
typedef __attribute__((ext_vector_type(4))) float f32x4;

__device__ inline u16 f2b(float f) {
  u32 u = __float_as_uint(f);
  u32 r = (u + 0x7fffu + ((u >> 16) & 1u)) >> 16;
  return (u16)r;
}
__device__ inline float b2f(u16 u) { return __uint_as_float(((u32)u) << 16); }
__device__ inline u32 pack2(float a, float b) {
  return (u32)f2b(a) | ((u32)f2b(b) << 16);
}

// K13: MFMA S-GEMM + exp + row-softmax -> S1g (bf16) + Z partial + MFMA T-partial
__global__ __launch_bounds__(256) void k13(const float* __restrict__ C,
                                           const float* __restrict__ Q,
                                           const float* __restrict__ w,
                                           const float* __restrict__ qmask,
                                           u16* __restrict__ S1g,
                                           float* __restrict__ Tu_part,
                                           float* __restrict__ Z_part, int B) {
  __shared__ u16 ldsA[128 * PAD];  // phase1: C^T[i][d]; phase3: Cnat[d][i]
  __shared__ u16 ldsB[64 * PAD];   // phase1: Qw^T[j][d]; phase3: E^T[j][i]
                                   // row pad (16B): sq partials, then inv[i]
  __shared__ float scL[128];
  __shared__ float sqs[64];
  __shared__ float mkS[64];
  int b = blockIdx.y, bx = blockIdx.x;
  int i0 = bx * 128, t = threadIdx.x;
  const float* Cb = C + (size_t)b * DD * LC;
  const float* Qb = Q + (size_t)b * DD * LQ;
  if (t < 64) mkS[t] = qmask[b * LQ + t];
  // --- phase 1 staging: C^T (bf16, transposed) + sc partial (fp32) ---
  int i_st = t & 127, dh = t >> 7;
  float scp = 0.f;
  {
    const float* Cp = Cb + (size_t)dh * 64 * LC + i0 + i_st;
#pragma unroll
    for (int dp = 0; dp < 32; ++dp) {
      int d = dh * 64 + 2 * dp;
      float c0 = Cp[(size_t)(2 * dp) * LC];
      float c1 = Cp[(size_t)(2 * dp + 1) * LC];
      scp = fmaf(c0, w[d], fmaf(c1, w[d + 1], scp));
      *(u32*)&ldsA[i_st * PAD + d] = pack2(c0, c1);
    }
    if (dh == 0) scL[i_st] = scp;
  }
  // Qw^T staging + sq partials (into row pad)
  {
    int j = t & 63, dg = t >> 6;
    const float* Qp = Qb + j;
    float sqp = 0.f;
#pragma unroll
    for (int dp = 0; dp < 16; ++dp) {
      int d = dg * 32 + 2 * dp;
      float q0 = Qp[(size_t)d * LQ];
      float q1 = Qp[(size_t)(d + 1) * LQ];
      sqp = fmaf(q0, w[DD + d], fmaf(q1, w[DD + d + 1], sqp));
      *(u32*)&ldsB[j * PAD + d] = pack2(q0 * w[2 * DD + d], q1 * w[2 * DD + d + 1]);
    }
    ((float*)&ldsB[j * PAD + 128])[dg] = sqp;
  }
  __syncthreads();
  if (dh == 1) scL[i_st] += scp;  // single writer per i; read after next barrier
  if (t < 64) {
    const float* pp = (const float*)&ldsB[t * PAD + 128];
    sqs[t] = pp[0] + pp[1] + pp[2] + pp[3];
  }
  // --- phase 2: S-GEMM (D[i][j] = sum_d C^T[i][d]*Qw^T[j][d]) ---
  int lane = t & 63, wv = t >> 6;
  int lr = lane & 15, kg = lane >> 4;
  f32x4 acc[2][4];
#pragma unroll
  for (int mt = 0; mt < 2; ++mt)
#pragma unroll
    for (int nt = 0; nt < 4; ++nt) acc[mt][nt] = (f32x4){0.f, 0.f, 0.f, 0.f};
#pragma unroll
  for (int ks = 0; ks < 4; ++ks) {
    bf16x8 af[2], bf[4];
#pragma unroll
    for (int mt = 0; mt < 2; ++mt)
      af[mt] = *(bf16x8*)&ldsA[((wv * 2 + mt) * 16 + lr) * PAD + ks * 32 + kg * 8];
#pragma unroll
    for (int nt = 0; nt < 4; ++nt)
      bf[nt] = *(bf16x8*)&ldsB[(nt * 16 + lr) * PAD + ks * 32 + kg * 8];
#pragma unroll
    for (int mt = 0; mt < 2; ++mt)
#pragma unroll
      for (int nt = 0; nt < 4; ++nt)
        acc[mt][nt] = __builtin_amdgcn_mfma_f32_16x16x32_bf16(af[mt], bf[nt],
                                                              acc[mt][nt], 0, 0, 0);
  }
  __syncthreads();  // all MFMA reads done; scL/sqs final
  // --- epilogue: E=exp(S+sc+sq); rowsum(mask*E) -> inv; E^T -> ldsB ---
#pragma unroll
  for (int mt = 0; mt < 2; ++mt) {
    int ib = (wv * 2 + mt) * 16 + kg * 4;
    float ev[4][4];
    float ps[4] = {0.f, 0.f, 0.f, 0.f};
#pragma unroll
    for (int nt = 0; nt < 4; ++nt) {
      int j = nt * 16 + lr;
      float sqv = sqs[j];
      float mkv = mkS[j];
#pragma unroll
      for (int r = 0; r < 4; ++r) {
        float e = __expf(acc[mt][nt][r] + scL[ib + r] + sqv);
        ev[nt][r] = e;
        ps[r] = fmaf(mkv, e, ps[r]);
      }
    }
#pragma unroll
    for (int r = 0; r < 4; ++r) {
      ps[r] += __shfl_xor(ps[r], 1, 64);
      ps[r] += __shfl_xor(ps[r], 2, 64);
      ps[r] += __shfl_xor(ps[r], 4, 64);
      ps[r] += __shfl_xor(ps[r], 8, 64);
    }
#pragma unroll
    for (int nt = 0; nt < 4; ++nt) {
      int j = nt * 16 + lr;
      u32 pk[2] = {pack2(ev[nt][0], ev[nt][1]), pack2(ev[nt][2], ev[nt][3])};
      *(uint2*)&ldsB[j * PAD + ib] = *(uint2*)pk;
    }
    if (lr == 0) {
#pragma unroll
      for (int r = 0; r < 4; ++r) {
        int i = ib + r;
        ((float*)&ldsB[(i & 63) * PAD + 128])[i >> 6] = 1.f / fmaxf(ps[r], 1e-30f);
      }
    }
  }
  // --- Cnat staging: C[d][i] bf16 (overlays ldsA) ---
  {
    int d = t >> 1, half = t & 1;
    const float* src = Cb + (size_t)d * LC + i0 + half * 64;
#pragma unroll
    for (int ip = 0; ip < 16; ++ip) {
      float4 v = *(const float4*)&src[ip * 4];
      u32 pk[2] = {pack2(v.x, v.y), pack2(v.z, v.w)};
      *(uint2*)&ldsA[d * PAD + half * 64 + ip * 4] = *(uint2*)pk;
    }
  }
  __syncthreads();
  // --- phase 3 ---
  // Z[j] over this block's 128 i
  if (t < 64) {
    const u32* row = (const u32*)&ldsB[t * PAD];
    float z = 0.f;
#pragma unroll
    for (int q = 0; q < 64; ++q) {
      u32 v = row[q];
      z += b2f((u16)v) + b2f((u16)(v >> 16));
    }
    Z_part[((size_t)bx * B + b) * LQ + t] = z;
  }
  // S1 dump: S1[i][j] = mask[j]*inv[i]*E[i][j], coalesced 64B/thread
  {
    int i = t >> 1, half = t & 1;
    float inv = ((float*)&ldsB[(i & 63) * PAD + 128])[i >> 6];
    u32 opk[16];
#pragma unroll
    for (int q = 0; q < 16; ++q) {
      int j = half * 32 + 2 * q;
      float a0 = b2f(ldsB[j * PAD + i]) * mkS[j] * inv;
      float a1 = b2f(ldsB[(j + 1) * PAD + i]) * mkS[j + 1] * inv;
      opk[q] = pack2(a0, a1);
    }
    u16* dst = S1g + ((size_t)b * LC + i0 + i) * LQ + half * 32;
#pragma unroll
    for (int q = 0; q < 4; ++q) *(uint4*)&dst[q * 8] = *(uint4*)&opk[q * 4];
  }
  // T-GEMM: Tp[j][d] = sum_i E[i][j]*C[d][i]
  f32x4 tacc[2][4];
#pragma unroll
  for (int mt = 0; mt < 2; ++mt)
#pragma unroll
    for (int nt = 0; nt < 4; ++nt) tacc[mt][nt] = (f32x4){0.f, 0.f, 0.f, 0.f};
#pragma unroll
  for (int ks = 0; ks < 4; ++ks) {
    bf16x8 af[2], bf[4];
#pragma unroll
    for (int mt = 0; mt < 2; ++mt)
      af[mt] = *(bf16x8*)&ldsA[((wv * 2 + mt) * 16 + lr) * PAD + ks * 32 + kg * 8];
#pragma unroll
    for (int nt = 0; nt < 4; ++nt)
      bf[nt] = *(bf16x8*)&ldsB[(nt * 16 + lr) * PAD + ks * 32 + kg * 8];
#pragma unroll
    for (int mt = 0; mt < 2; ++mt)
#pragma unroll
      for (int nt = 0; nt < 4; ++nt)
        tacc[mt][nt] = __builtin_amdgcn_mfma_f32_16x16x32_bf16(af[mt], bf[nt],
                                                               tacc[mt][nt], 0, 0, 0);
  }
  float* Tp = Tu_part + ((size_t)bx * B + b) * LQ * DD;
#pragma unroll
  for (int mt = 0; mt < 2; ++mt)
#pragma unroll
    for (int nt = 0; nt < 4; ++nt) {
      int j = nt * 16 + lr;
      int db = (wv * 2 + mt) * 16 + kg * 4;
      *(f32x4*)&Tp[(size_t)j * DD + db] = tacc[mt][nt];
    }
}

// K3b: sum Tu partials, scale by Zi=1/sum(Z_part), write TzT[b][d][j] bf16
__global__ __launch_bounds__(256) void k3b(const float* __restrict__ Tu_part,
                                           const float* __restrict__ Z_part,
                                           u16* __restrict__ TzT, int B) {
  __shared__ float Tsm[16][68];
  __shared__ float ziL[64];
  int b = blockIdx.y, d0 = blockIdx.x * 16;
  int t = threadIdx.x;
  int dd = t & 15, jg = t >> 4;
  float acc[4] = {};
#pragma unroll
  for (int p = 0; p < NPART; ++p) {
    const float* src = Tu_part + ((size_t)p * B + b) * LQ * DD + d0 + dd;
#pragma unroll
    for (int jj = 0; jj < 4; ++jj) acc[jj] += src[(jg * 4 + jj) * DD];
  }
  if (t < 64) {
    float z = 0.f;
#pragma unroll
    for (int p = 0; p < NPART; ++p) z += Z_part[((size_t)p * B + b) * LQ + t];
    ziL[t] = 1.f / z;
  }
  *(float4*)&Tsm[dd][jg * 4] = make_float4(acc[0], acc[1], acc[2], acc[3]);
  __syncthreads();
  if (t < 128) {
    int d = t >> 3, seg = t & 7;
    u32 pk[4];
#pragma unroll
    for (int q = 0; q < 4; ++q) {
      int j = seg * 8 + q * 2;
      pk[q] = pack2(Tsm[d][j] * ziL[j], Tsm[d][j + 1] * ziL[j + 1]);
    }
    *(uint4*)&TzT[((size_t)b * DD + d0 + d) * LQ + seg * 8] = *(uint4*)pk;
  }
}

// K4: LDS-free, barrier-free. A = S1@Qt, Bm = S1@Tz; out = [C, A, C*A, C*Bm]
__global__ __launch_bounds__(256) void k4(const u16* __restrict__ S1g,
                                          const float* __restrict__ Q,
                                          const u16* __restrict__ TzT,
                                          const float* __restrict__ C,
                                          float* __restrict__ out) {
  int b = blockIdx.y, i0 = blockIdx.x * 128, t = threadIdx.x;
  int lane = t & 63, wv = t >> 6;
  int lr = lane & 15, kg = lane >> 4;
  // B-operand frags: S1 rows i, contiguous j
  bf16x8 Bf[2][2];
#pragma unroll
  for (int it = 0; it < 2; ++it) {
    size_t ri = (size_t)b * LC + i0 + wv * 32 + it * 16 + lr;
#pragma unroll
    for (int ks = 0; ks < 2; ++ks)
      Bf[it][ks] = *(const bf16x8*)&S1g[ri * LQ + ks * 32 + kg * 8];
  }
  const float* Qb = Q + (size_t)b * DD * LQ;
  const u16* Tzb = TzT + (size_t)b * DD * LQ;
  const float* Cb = C + (size_t)b * DD * LC + i0;
  float* outb = out + (size_t)b * 4 * DD * LC + i0;
#pragma unroll
  for (int dt = 0; dt < 8; ++dt) {
    int da = dt * 16 + lr;
    bf16x8 QA[2], TA[2];
#pragma unroll
    for (int ks = 0; ks < 2; ++ks) {
      const float* qp = Qb + da * LQ + ks * 32 + kg * 8;
      float4 q0 = *(const float4*)qp;
      float4 q1 = *(const float4*)(qp + 4);
      u32 pk[4] = {pack2(q0.x, q0.y), pack2(q0.z, q0.w), pack2(q1.x, q1.y),
                   pack2(q1.z, q1.w)};
      QA[ks] = *(bf16x8*)pk;
      TA[ks] = *(const bf16x8*)&Tzb[da * LQ + ks * 32 + kg * 8];
    }
#pragma unroll
    for (int it = 0; it < 2; ++it) {
      f32x4 accA = {0.f, 0.f, 0.f, 0.f}, accB = {0.f, 0.f, 0.f, 0.f};
      accA = __builtin_amdgcn_mfma_f32_16x16x32_bf16(QA[0], Bf[it][0], accA, 0, 0, 0);
      accA = __builtin_amdgcn_mfma_f32_16x16x32_bf16(QA[1], Bf[it][1], accA, 0, 0, 0);
      accB = __builtin_amdgcn_mfma_f32_16x16x32_bf16(TA[0], Bf[it][0], accB, 0, 0, 0);
      accB = __builtin_amdgcn_mfma_f32_16x16x32_bf16(TA[1], Bf[it][1], accB, 0, 0, 0);
      int ii = wv * 32 + it * 16 + lr;
#pragma unroll
      for (int r = 0; r < 4; ++r) {
        int d = dt * 16 + kg * 4 + r;
        float c = Cb[(size_t)d * LC + ii];
        float a = accA[r], bm = accB[r];
        outb[(size_t)d * LC + ii] = c;
        outb[(size_t)(DD + d) * LC + ii] = a;
        outb[(size_t)(2 * DD + d) * LC + ii] = c * a;
        outb[(size_t)(3 * DD + d) * LC + ii] = c * bm;
      }
    }
  }
}

extern "C" void kernel_launch(void* const* d_in, const int* in_sizes, int n_in,
                              void* d_out, int out_size, void* d_ws, size_t ws_size,
                              hipStream_t stream) {
  const float* C = (const float*)d_in[0];
  const float* Q = (const float*)d_in[1];
  const float* qmask = (const float*)d_in[2];
  const float* w = (const float*)d_in[3];
  float* out = (float*)d_out;
  int B = in_sizes[2] / LQ;

  char* p = (char*)d_ws;
  u16* S1g = (u16*)p;           p += (size_t)B * LC * LQ * 2;
  u16* TzT = (u16*)p;           p += (size_t)B * DD * LQ * 2;
  float* Tu_part = (float*)p;   p += (size_t)NPART * B * LQ * DD * 4;
  float* Z_part = (float*)p;

  k13<<<dim3(NPART, B), 256, 0, stream>>>(C, Q, w, qmask, S1g, Tu_part, Z_part, B);
  k3b<<<dim3(DD / 16, B), 256, 0, stream>>>(Tu_part, Z_part, TzT, B);
  k4<<<dim3(LC / 128, B), 256, 0, stream>>>(S1g, Q, TzT, C, out);
}